// Round 4
// baseline (8974.948 us; speedup 1.0000x reference)
//
#include <hip/hip_runtime.h>
#include <hip/hip_fp16.h>
#include <cstddef>
#include <cstdint>

#define U_DIM 256
#define G_DIM 1024          // 4*U
#define T_DIM 512
#define B_DIM 64
#define TC    128           // timesteps per chunk
#define NCHUNK (T_DIM / TC)

// Weight residency split (32 groups of 8 k-values each = K=256)
#define NG_TOT 32
#define NG_REG 23           // groups  0..22 -> VGPRs/AGPRs (92 regs)
#define NG_LDS 9            // groups 23..31 -> LDS (144 KB)

typedef _Float16 half2v __attribute__((ext_vector_type(2)));

__device__ __forceinline__ float fsig(float x) {
    return 1.0f / (1.0f + __expf(-x));
}
__device__ __forceinline__ float ftanh(float x) {
    return 2.0f * fsig(2.0f * x) - 1.0f;
}

// ---------------------------------------------------------------------------
// Pack U [256,1024] fp32 -> P: [32 groups][1024 cols] of uint4.
// P[g][n] holds f16(U[8g+0..8g+7][n]) packed 2-per-u32.
// ---------------------------------------------------------------------------
__global__ __launch_bounds__(256)
void pack_w(const float* __restrict__ U, uint4* __restrict__ P)
{
    const int idx = blockIdx.x * 256 + threadIdx.x;   // 0..32767
    const int g = idx >> 10;
    const int n = idx & 1023;
    uint vals[4];
    #pragma unroll
    for (int j = 0; j < 4; ++j) {
        const int k = g * 8 + j * 2;
        const __half a = __float2half_rn(U[(size_t)k * G_DIM + n]);
        const __half b = __float2half_rn(U[(size_t)(k + 1) * G_DIM + n]);
        const unsigned short ua = __builtin_bit_cast(unsigned short, a);
        const unsigned short ub = __builtin_bit_cast(unsigned short, b);
        vals[j] = (uint)ua | ((uint)ub << 16);
    }
    P[idx] = make_uint4(vals[0], vals[1], vals[2], vals[3]);
}

// 8 MACs: acc += sum_j f16(h)[j] * f16(w)[j]   (both packed 2-per-u32)
__device__ __forceinline__ float mac8(float acc, uint4 w, uint4 h)
{
#if __has_builtin(__builtin_amdgcn_fdot2)
    acc = __builtin_amdgcn_fdot2(__builtin_bit_cast(half2v, h.x),
                                 __builtin_bit_cast(half2v, w.x), acc, false);
    acc = __builtin_amdgcn_fdot2(__builtin_bit_cast(half2v, h.y),
                                 __builtin_bit_cast(half2v, w.y), acc, false);
    acc = __builtin_amdgcn_fdot2(__builtin_bit_cast(half2v, h.z),
                                 __builtin_bit_cast(half2v, w.z), acc, false);
    acc = __builtin_amdgcn_fdot2(__builtin_bit_cast(half2v, h.w),
                                 __builtin_bit_cast(half2v, w.w), acc, false);
#else
    const uint wv[4] = {w.x, w.y, w.z, w.w};
    const uint hv[4] = {h.x, h.y, h.z, h.w};
    #pragma unroll
    for (int j = 0; j < 4; ++j) {
        const __half2 wp = __builtin_bit_cast(__half2, wv[j]);
        const __half2 hp = __builtin_bit_cast(__half2, hv[j]);
        acc += __half2float(hp.x) * __half2float(wp.x);
        acc += __half2float(hp.y) * __half2float(wp.y);
    }
#endif
    return acc;
}

// ---------------------------------------------------------------------------
// Sequential LSTM for one T-chunk, f16 weights FULLY resident (regs + LDS).
// One block per batch row, 1024 threads, thread n owns gate-column n.
// ---------------------------------------------------------------------------
__global__
__attribute__((amdgpu_flat_work_group_size(1024, 1024)))
__attribute__((amdgpu_waves_per_eu(4, 4)))
void lstm_chunk(const float* __restrict__ xz, const uint4* __restrict__ P,
                const float* __restrict__ res, float* __restrict__ outseq,
                float* __restrict__ hstate, float* __restrict__ cstate,
                int t0)
{
    const int b = blockIdx.x;
    const int n = threadIdx.x;

    __shared__ __align__(16) uint hq[U_DIM / 2];   // h as packed f16 (512 B)
    __shared__ float csh[U_DIM];
    __shared__ float zsh[G_DIM];
    __shared__ uint4 wlds[NG_LDS][G_DIM];          // 144 KB

    // ---- load resident weights ----
    uint4 wreg[NG_REG];
    #pragma unroll
    for (int g = 0; g < NG_REG; ++g) wreg[g] = P[(size_t)g * G_DIM + n];
    // Pin: values now originate from the asm, so the loads above cannot be
    // re-materialized inside the time loop (overflow goes to AGPRs, not L2).
    #pragma unroll
    for (int g = 0; g < NG_REG; ++g)
        asm("" : "+v"(wreg[g].x), "+v"(wreg[g].y), "+v"(wreg[g].z), "+v"(wreg[g].w));
    #pragma unroll
    for (int g = 0; g < NG_LDS; ++g) wlds[g][n] = P[(size_t)(NG_REG + g) * G_DIM + n];

    if (n < U_DIM) {
        float h0, c0;
        if (t0 == 0) { h0 = 0.0f; c0 = 0.0f; }
        else         { h0 = hstate[b * U_DIM + n]; c0 = cstate[b * U_DIM + n]; }
        csh[n] = c0;
        ((__half*)hq)[n] = __float2half_rn(h0);
    }
    __syncthreads();

    const int gate = n >> 8;   // 0=i, 1=f, 2=g(tanh), 3=o

    const float* __restrict__ xzp = xz + (size_t)(b * TC) * G_DIM + n;
    float xzcur = xzp[0];

    for (int tl = 0; tl < TC; ++tl) {
        float acc = xzcur;
        // prefetch next step's xz (independent of LDS/h; latency hides under macs)
        const int tn = (tl + 1 < TC) ? (tl + 1) : (TC - 1);
        xzcur = xzp[(size_t)tn * G_DIM];

        // register-resident groups
        #pragma unroll
        for (int g = 0; g < NG_REG; ++g) {
            const uint4 h = *(const uint4*)&hq[g * 4];
            acc = mac8(acc, wreg[g], h);
        }
        // LDS-resident groups
        #pragma unroll
        for (int g = 0; g < NG_LDS; ++g) {
            const uint4 h = *(const uint4*)&hq[(NG_REG + g) * 4];
            acc = mac8(acc, wlds[g][n], h);
        }

        // gate nonlinearity, all 1024 threads in parallel
        const float a = (gate == 2) ? ftanh(acc) : fsig(acc);
        zsh[n] = a;
        __syncthreads();

        if (n < U_DIM) {
            const float iv = zsh[n];
            const float fv = zsh[n + 256];
            const float gv = zsh[n + 512];
            const float ov = zsh[n + 768];
            const float cc = fv * csh[n] + iv * gv;
            const float hh = ov * ftanh(cc);
            csh[n] = cc;
            ((__half*)hq)[n] = __float2half_rn(hh);
            if (outseq) {
                const size_t oidx = (size_t)(b * T_DIM + t0 + tl) * U_DIM + n;
                outseq[oidx] = hh + (res ? res[oidx] : 0.0f);
            }
        }
        __syncthreads();
    }

    if (n < U_DIM) {
        hstate[b * U_DIM + n] = __half2float(((const __half*)hq)[n]);
        cstate[b * U_DIM + n] = csh[n];
    }
}

// ---------------------------------------------------------------------------
// GEMM: out[m, :] = A[row(m), :] @ W + bias, for one T-chunk. (unchanged)
// ---------------------------------------------------------------------------
__global__ __launch_bounds__(256)
void gemm_proj(const float* __restrict__ A, const float* __restrict__ W,
               const float* __restrict__ bias, float* __restrict__ out,
               int t0)
{
    __shared__ float As[16][64];
    __shared__ float Bs[16][64];

    const int tid = threadIdx.x;
    const int bm = blockIdx.y * 64;
    const int bn = blockIdx.x * 64;

    const int arow = tid >> 2;
    const int acol = (tid & 3) << 2;
    const int m_local = bm + arow;
    const int b  = m_local >> 7;
    const int tl = m_local & (TC - 1);
    const float* arow_ptr = A + (size_t)(b * T_DIM + t0 + tl) * U_DIM;

    const int brow = tid >> 4;
    const int bcol = (tid & 15) << 2;

    const int tr = tid >> 4;
    const int tc = tid & 15;

    float acc[4][4] = {};

    for (int k0 = 0; k0 < U_DIM; k0 += 16) {
        const float4 a4 = *(const float4*)(arow_ptr + k0 + acol);
        const float4 b4 = *(const float4*)(W + (size_t)(k0 + brow) * G_DIM + bn + bcol);
        As[acol + 0][arow] = a4.x;
        As[acol + 1][arow] = a4.y;
        As[acol + 2][arow] = a4.z;
        As[acol + 3][arow] = a4.w;
        *(float4*)&Bs[brow][bcol] = b4;
        __syncthreads();
        #pragma unroll
        for (int k = 0; k < 16; ++k) {
            const float4 av = *(const float4*)&As[k][tr << 2];
            const float4 bv = *(const float4*)&Bs[k][tc << 2];
            const float a_[4] = {av.x, av.y, av.z, av.w};
            const float b_[4] = {bv.x, bv.y, bv.z, bv.w};
            #pragma unroll
            for (int i = 0; i < 4; ++i)
                #pragma unroll
                for (int j = 0; j < 4; ++j)
                    acc[i][j] += a_[i] * b_[j];
        }
        __syncthreads();
    }

    const int oc = bn + (tc << 2);
    const float4 bia = *(const float4*)(bias + oc);
    #pragma unroll
    for (int i = 0; i < 4; ++i) {
        const int m = bm + (tr << 2) + i;
        float4 o;
        o.x = acc[i][0] + bia.x;
        o.y = acc[i][1] + bia.y;
        o.z = acc[i][2] + bia.z;
        o.w = acc[i][3] + bia.w;
        *(float4*)(out + (size_t)m * G_DIM + oc) = o;
    }
}

// ---------------------------------------------------------------------------
// Final: y[b,o] = sum_j (h1[b,j] + h2[b, j%256]) * Wd[j,o] + bd[o]  (unchanged)
// ---------------------------------------------------------------------------
__global__ __launch_bounds__(256)
void final_proj(const float* __restrict__ h1, const float* __restrict__ h2,
                const float* __restrict__ Wd, const float* __restrict__ bd,
                float* __restrict__ y)
{
    const int b = blockIdx.x;
    const int tid = threadIdx.x;
    const int JTOT = T_DIM * U_DIM;   // 131072

    float a0 = 0.f, a1 = 0.f, a2 = 0.f, a3 = 0.f;
    const float* hb = h1 + (size_t)b * JTOT;
    const float* h2b = h2 + (size_t)b * U_DIM;

    for (int j = tid; j < JTOT; j += 256) {
        const float v = hb[j] + h2b[j & (U_DIM - 1)];
        const float4 w = *(const float4*)&Wd[(size_t)j * 4];
        a0 += v * w.x;
        a1 += v * w.y;
        a2 += v * w.z;
        a3 += v * w.w;
    }

    __shared__ float red[256][4];
    red[tid][0] = a0; red[tid][1] = a1; red[tid][2] = a2; red[tid][3] = a3;
    __syncthreads();
    for (int s = 128; s > 0; s >>= 1) {
        if (tid < s) {
            #pragma unroll
            for (int o = 0; o < 4; ++o) red[tid][o] += red[tid + s][o];
        }
        __syncthreads();
    }
    if (tid < 4) y[b * 4 + tid] = red[0][tid] + bd[tid];
}

// ---------------------------------------------------------------------------
extern "C" void kernel_launch(void* const* d_in, const int* in_sizes, int n_in,
                              void* d_out, int out_size, void* d_ws, size_t ws_size,
                              hipStream_t stream)
{
    (void)in_sizes; (void)n_in; (void)out_size; (void)ws_size;

    const float* x  = (const float*)d_in[0];
    const float* Wr = (const float*)d_in[1];
    const float* Ur = (const float*)d_in[2];
    const float* br = (const float*)d_in[3];
    const float* Wn = (const float*)d_in[4];
    const float* Un = (const float*)d_in[5];
    const float* bn = (const float*)d_in[6];
    const float* Wd = (const float*)d_in[7];
    const float* bd = (const float*)d_in[8];
    float* y = (float*)d_out;

    float* ws = (float*)d_ws;
    const size_t CHUNK_ELEMS = (size_t)B_DIM * TC * G_DIM;      // 8,388,608
    const size_t SEQ_ELEMS   = (size_t)B_DIM * T_DIM * U_DIM;   // 8,388,608
    const size_t BHID        = (size_t)B_DIM * U_DIM;           // 16,384
    float* xzbuf = ws;
    float* h0    = xzbuf + CHUNK_ELEMS;
    float* h1    = h0 + SEQ_ELEMS;
    float* hs    = h1 + SEQ_ELEMS;
    float* cs    = hs + BHID;
    uint4* Pr    = (uint4*)(cs + BHID);            // 32*1024 uint4 = 512 KB
    uint4* Pn    = Pr + (size_t)NG_TOT * G_DIM;    // 512 KB
    // total ws use ~= 97.2 MiB

    // ---- pack recurrent weights to f16 ----
    pack_w<<<128, 256, 0, stream>>>(Ur, Pr);
    pack_w<<<128, 256, 0, stream>>>(Un, Pn);

    dim3 ggrid(G_DIM / 64, (B_DIM * TC) / 64);   // (16, 128)

    // ---- layer 0: shared LSTM on x, no residual, outputs h0 ----
    for (int ch = 0; ch < NCHUNK; ++ch) {
        const int t0 = ch * TC;
        gemm_proj<<<ggrid, 256, 0, stream>>>(x, Wr, br, xzbuf, t0);
        lstm_chunk<<<B_DIM, 1024, 0, stream>>>(xzbuf, Pr, nullptr, h0, hs, cs, t0);
    }
    // ---- layer 1: same shared weights on h0, residual add, outputs h1 ----
    for (int ch = 0; ch < NCHUNK; ++ch) {
        const int t0 = ch * TC;
        gemm_proj<<<ggrid, 256, 0, stream>>>(h0, Wr, br, xzbuf, t0);
        lstm_chunk<<<B_DIM, 1024, 0, stream>>>(xzbuf, Pr, h0, h1, hs, cs, t0);
    }
    // ---- layer 2: Wn/Un/bn on h1, keep only last hidden state (in hs) ----
    for (int ch = 0; ch < NCHUNK; ++ch) {
        const int t0 = ch * TC;
        gemm_proj<<<ggrid, 256, 0, stream>>>(h1, Wn, bn, xzbuf, t0);
        lstm_chunk<<<B_DIM, 1024, 0, stream>>>(xzbuf, Pn, nullptr, nullptr, hs, cs, t0);
    }
    // ---- final projection ----
    final_proj<<<B_DIM, 256, 0, stream>>>(h1, hs, Wd, bd, y);
}

// Round 5
// 4101.070 us; speedup vs baseline: 2.1884x; 2.1884x over previous
//
#include <hip/hip_runtime.h>
#include <hip/hip_fp16.h>
#include <cstddef>
#include <cstdint>

#define U_DIM 256
#define G_DIM 1024          // 4*U
#define T_DIM 512
#define B_DIM 64
#define TC    128           // timesteps per chunk
#define NCHUNK (T_DIM / TC)

// Weight residency split (32 groups of 8 k-values each = K=256)
// 512 threads/block, 2 columns per thread -> per-thread: 2*NG_REG uint4 in regs.
#define NG_TOT 32
#define NG_REG 24           // groups  0..23 -> regs (24*2*4 = 192 VGPRs/thread)
#define NG_LDS 8            // groups 24..31 -> LDS (8*1024*16 B = 128 KB)

typedef _Float16 half2v __attribute__((ext_vector_type(2)));

__device__ __forceinline__ float fsig(float x) {
    return 1.0f / (1.0f + __expf(-x));
}
__device__ __forceinline__ float ftanh(float x) {
    return 2.0f * fsig(2.0f * x) - 1.0f;
}

// ---------------------------------------------------------------------------
// Pack U [256,1024] fp32 -> P: [32 groups][1024 cols] of uint4.
// P[g][n] holds f16(U[8g+0..8g+7][n]) packed 2-per-u32.
// ---------------------------------------------------------------------------
__global__ __launch_bounds__(256)
void pack_w(const float* __restrict__ U, uint4* __restrict__ P)
{
    const int idx = blockIdx.x * 256 + threadIdx.x;   // 0..32767
    const int g = idx >> 10;
    const int n = idx & 1023;
    uint vals[4];
    #pragma unroll
    for (int j = 0; j < 4; ++j) {
        const int k = g * 8 + j * 2;
        const __half a = __float2half_rn(U[(size_t)k * G_DIM + n]);
        const __half b = __float2half_rn(U[(size_t)(k + 1) * G_DIM + n]);
        const unsigned short ua = __builtin_bit_cast(unsigned short, a);
        const unsigned short ub = __builtin_bit_cast(unsigned short, b);
        vals[j] = (uint)ua | ((uint)ub << 16);
    }
    P[idx] = make_uint4(vals[0], vals[1], vals[2], vals[3]);
}

// 8 MACs: acc += sum_j f16(h)[j] * f16(w)[j]   (both packed 2-per-u32)
__device__ __forceinline__ float mac8(float acc, uint4 w, uint4 h)
{
#if __has_builtin(__builtin_amdgcn_fdot2)
    acc = __builtin_amdgcn_fdot2(__builtin_bit_cast(half2v, h.x),
                                 __builtin_bit_cast(half2v, w.x), acc, false);
    acc = __builtin_amdgcn_fdot2(__builtin_bit_cast(half2v, h.y),
                                 __builtin_bit_cast(half2v, w.y), acc, false);
    acc = __builtin_amdgcn_fdot2(__builtin_bit_cast(half2v, h.z),
                                 __builtin_bit_cast(half2v, w.z), acc, false);
    acc = __builtin_amdgcn_fdot2(__builtin_bit_cast(half2v, h.w),
                                 __builtin_bit_cast(half2v, w.w), acc, false);
#else
    const uint wv[4] = {w.x, w.y, w.z, w.w};
    const uint hv[4] = {h.x, h.y, h.z, h.w};
    #pragma unroll
    for (int j = 0; j < 4; ++j) {
        const __half2 wp = __builtin_bit_cast(__half2, wv[j]);
        const __half2 hp = __builtin_bit_cast(__half2, hv[j]);
        acc += __half2float(hp.x) * __half2float(wp.x);
        acc += __half2float(hp.y) * __half2float(wp.y);
    }
#endif
    return acc;
}

// ---------------------------------------------------------------------------
// Sequential LSTM for one T-chunk, f16 weights FULLY resident (regs + LDS).
// 64 blocks (one per batch row) x 512 threads; thread t owns gate-columns
// t and t+512. 512 threads = 8 waves = 2 waves/SIMD -> 256-reg cap, so the
// 192-reg weight array physically fits.
// ---------------------------------------------------------------------------
__global__
__attribute__((amdgpu_flat_work_group_size(512, 512)))
__attribute__((amdgpu_waves_per_eu(2, 2)))
void lstm_chunk(const float* __restrict__ xz, const uint4* __restrict__ P,
                const float* __restrict__ res, float* __restrict__ outseq,
                float* __restrict__ hstate, float* __restrict__ cstate,
                int t0)
{
    const int b = blockIdx.x;
    const int t = threadIdx.x;      // 0..511
    const int n0 = t;               // column A: gate i (t<256) / f (t>=256)
    const int n1 = t + 512;         // column B: gate g (t<256) / o (t>=256)

    __shared__ __align__(16) uint hq[U_DIM / 2];   // h as packed f16 (512 B)
    __shared__ float csh[U_DIM];
    __shared__ float zsh[G_DIM];
    __shared__ uint4 wlds[NG_LDS][G_DIM];          // 128 KB

    // ---- load resident weights (one-time per dispatch) ----
    uint4 wA[NG_REG], wB[NG_REG];
    #pragma unroll
    for (int g = 0; g < NG_REG; ++g) {
        wA[g] = P[(size_t)g * G_DIM + n0];
        wB[g] = P[(size_t)g * G_DIM + n1];
    }
    #pragma unroll
    for (int g = 0; g < NG_LDS; ++g) {
        wlds[g][n0] = P[(size_t)(NG_REG + g) * G_DIM + n0];
        wlds[g][n1] = P[(size_t)(NG_REG + g) * G_DIM + n1];
    }

    if (t < U_DIM) {
        float h0, c0;
        if (t0 == 0) { h0 = 0.0f; c0 = 0.0f; }
        else         { h0 = hstate[b * U_DIM + t]; c0 = cstate[b * U_DIM + t]; }
        csh[t] = c0;
        ((__half*)hq)[t] = __float2half_rn(h0);
    }
    __syncthreads();

    const float* __restrict__ xzb = xz + (size_t)(b * TC) * G_DIM;
    const float* __restrict__ resb = res ? (res + (size_t)(b * T_DIM + t0) * U_DIM) : nullptr;

    float cur0 = xzb[n0];
    float cur1 = xzb[n1];
    float resv = (resb && t < U_DIM) ? resb[t] : 0.0f;

    for (int tl = 0; tl < TC; ++tl) {
        float acc0 = cur0;
        float acc1 = cur1;

        // prefetch next step's xz / residual (latency hides under the dots)
        const int tn = (tl + 1 < TC) ? (tl + 1) : (TC - 1);
        cur0 = xzb[(size_t)tn * G_DIM + n0];
        cur1 = xzb[(size_t)tn * G_DIM + n1];
        const float resnext = (resb && t < U_DIM) ? resb[(size_t)tn * U_DIM + t] : 0.0f;

        const uint4* __restrict__ hp = (const uint4*)hq;

        // register-resident groups
        #pragma unroll
        for (int g = 0; g < NG_REG; ++g) {
            const uint4 h4 = hp[g];
            acc0 = mac8(acc0, wA[g], h4);
            acc1 = mac8(acc1, wB[g], h4);
        }
        // LDS-resident groups
        #pragma unroll
        for (int g = 0; g < NG_LDS; ++g) {
            const uint4 h4 = hp[NG_REG + g];
            acc0 = mac8(acc0, wlds[g][n0], h4);
            acc1 = mac8(acc1, wlds[g][n1], h4);
        }

        // activations (wave-uniform branch: waves 0-3 have t<256)
        zsh[n0] = fsig(acc0);
        zsh[n1] = (t < U_DIM) ? ftanh(acc1) : fsig(acc1);
        __syncthreads();

        if (t < U_DIM) {
            const float iv = zsh[t];
            const float fv = zsh[t + 256];
            const float gv = zsh[t + 512];
            const float ov = zsh[t + 768];
            const float cc = fv * csh[t] + iv * gv;
            const float hh = ov * ftanh(cc);
            csh[t] = cc;
            ((__half*)hq)[t] = __float2half_rn(hh);
            if (outseq) {
                const size_t oidx = (size_t)(b * T_DIM + t0 + tl) * U_DIM + t;
                outseq[oidx] = hh + resv;
            }
        }
        resv = resnext;
        __syncthreads();
    }

    if (t < U_DIM) {
        hstate[b * U_DIM + t] = __half2float(((const __half*)hq)[t]);
        cstate[b * U_DIM + t] = csh[t];
    }
}

// ---------------------------------------------------------------------------
// GEMM: out[m, :] = A[row(m), :] @ W + bias, for one T-chunk. (unchanged)
// ---------------------------------------------------------------------------
__global__ __launch_bounds__(256)
void gemm_proj(const float* __restrict__ A, const float* __restrict__ W,
               const float* __restrict__ bias, float* __restrict__ out,
               int t0)
{
    __shared__ float As[16][64];
    __shared__ float Bs[16][64];

    const int tid = threadIdx.x;
    const int bm = blockIdx.y * 64;
    const int bn = blockIdx.x * 64;

    const int arow = tid >> 2;
    const int acol = (tid & 3) << 2;
    const int m_local = bm + arow;
    const int b  = m_local >> 7;
    const int tl = m_local & (TC - 1);
    const float* arow_ptr = A + (size_t)(b * T_DIM + t0 + tl) * U_DIM;

    const int brow = tid >> 4;
    const int bcol = (tid & 15) << 2;

    const int tr = tid >> 4;
    const int tc = tid & 15;

    float acc[4][4] = {};

    for (int k0 = 0; k0 < U_DIM; k0 += 16) {
        const float4 a4 = *(const float4*)(arow_ptr + k0 + acol);
        const float4 b4 = *(const float4*)(W + (size_t)(k0 + brow) * G_DIM + bn + bcol);
        As[acol + 0][arow] = a4.x;
        As[acol + 1][arow] = a4.y;
        As[acol + 2][arow] = a4.z;
        As[acol + 3][arow] = a4.w;
        *(float4*)&Bs[brow][bcol] = b4;
        __syncthreads();
        #pragma unroll
        for (int k = 0; k < 16; ++k) {
            const float4 av = *(const float4*)&As[k][tr << 2];
            const float4 bv = *(const float4*)&Bs[k][tc << 2];
            const float a_[4] = {av.x, av.y, av.z, av.w};
            const float b_[4] = {bv.x, bv.y, bv.z, bv.w};
            #pragma unroll
            for (int i = 0; i < 4; ++i)
                #pragma unroll
                for (int j = 0; j < 4; ++j)
                    acc[i][j] += a_[i] * b_[j];
        }
        __syncthreads();
    }

    const int oc = bn + (tc << 2);
    const float4 bia = *(const float4*)(bias + oc);
    #pragma unroll
    for (int i = 0; i < 4; ++i) {
        const int m = bm + (tr << 2) + i;
        float4 o;
        o.x = acc[i][0] + bia.x;
        o.y = acc[i][1] + bia.y;
        o.z = acc[i][2] + bia.z;
        o.w = acc[i][3] + bia.w;
        *(float4*)(out + (size_t)m * G_DIM + oc) = o;
    }
}

// ---------------------------------------------------------------------------
// Final: y[b,o] = sum_j (h1[b,j] + h2[b, j%256]) * Wd[j,o] + bd[o]  (unchanged)
// ---------------------------------------------------------------------------
__global__ __launch_bounds__(256)
void final_proj(const float* __restrict__ h1, const float* __restrict__ h2,
                const float* __restrict__ Wd, const float* __restrict__ bd,
                float* __restrict__ y)
{
    const int b = blockIdx.x;
    const int tid = threadIdx.x;
    const int JTOT = T_DIM * U_DIM;   // 131072

    float a0 = 0.f, a1 = 0.f, a2 = 0.f, a3 = 0.f;
    const float* hb = h1 + (size_t)b * JTOT;
    const float* h2b = h2 + (size_t)b * U_DIM;

    for (int j = tid; j < JTOT; j += 256) {
        const float v = hb[j] + h2b[j & (U_DIM - 1)];
        const float4 w = *(const float4*)&Wd[(size_t)j * 4];
        a0 += v * w.x;
        a1 += v * w.y;
        a2 += v * w.z;
        a3 += v * w.w;
    }

    __shared__ float red[256][4];
    red[tid][0] = a0; red[tid][1] = a1; red[tid][2] = a2; red[tid][3] = a3;
    __syncthreads();
    for (int s = 128; s > 0; s >>= 1) {
        if (tid < s) {
            #pragma unroll
            for (int o = 0; o < 4; ++o) red[tid][o] += red[tid + s][o];
        }
        __syncthreads();
    }
    if (tid < 4) y[b * 4 + tid] = red[0][tid] + bd[tid];
}

// ---------------------------------------------------------------------------
extern "C" void kernel_launch(void* const* d_in, const int* in_sizes, int n_in,
                              void* d_out, int out_size, void* d_ws, size_t ws_size,
                              hipStream_t stream)
{
    (void)in_sizes; (void)n_in; (void)out_size; (void)ws_size;

    const float* x  = (const float*)d_in[0];
    const float* Wr = (const float*)d_in[1];
    const float* Ur = (const float*)d_in[2];
    const float* br = (const float*)d_in[3];
    const float* Wn = (const float*)d_in[4];
    const float* Un = (const float*)d_in[5];
    const float* bn = (const float*)d_in[6];
    const float* Wd = (const float*)d_in[7];
    const float* bd = (const float*)d_in[8];
    float* y = (float*)d_out;

    float* ws = (float*)d_ws;
    const size_t CHUNK_ELEMS = (size_t)B_DIM * TC * G_DIM;      // 8,388,608
    const size_t SEQ_ELEMS   = (size_t)B_DIM * T_DIM * U_DIM;   // 8,388,608
    const size_t BHID        = (size_t)B_DIM * U_DIM;           // 16,384
    float* xzbuf = ws;
    float* h0    = xzbuf + CHUNK_ELEMS;
    float* h1    = h0 + SEQ_ELEMS;
    float* hs    = h1 + SEQ_ELEMS;
    float* cs    = hs + BHID;
    uint4* Pr    = (uint4*)(cs + BHID);            // 32*1024 uint4 = 512 KB
    uint4* Pn    = Pr + (size_t)NG_TOT * G_DIM;    // 512 KB
    // total ws use ~= 97.2 MiB

    // ---- pack recurrent weights to f16 ----
    pack_w<<<128, 256, 0, stream>>>(Ur, Pr);
    pack_w<<<128, 256, 0, stream>>>(Un, Pn);

    dim3 ggrid(G_DIM / 64, (B_DIM * TC) / 64);   // (16, 128)

    // ---- layer 0: shared LSTM on x, no residual, outputs h0 ----
    for (int ch = 0; ch < NCHUNK; ++ch) {
        const int t0 = ch * TC;
        gemm_proj<<<ggrid, 256, 0, stream>>>(x, Wr, br, xzbuf, t0);
        lstm_chunk<<<B_DIM, 512, 0, stream>>>(xzbuf, Pr, nullptr, h0, hs, cs, t0);
    }
    // ---- layer 1: same shared weights on h0, residual add, outputs h1 ----
    for (int ch = 0; ch < NCHUNK; ++ch) {
        const int t0 = ch * TC;
        gemm_proj<<<ggrid, 256, 0, stream>>>(h0, Wr, br, xzbuf, t0);
        lstm_chunk<<<B_DIM, 512, 0, stream>>>(xzbuf, Pr, h0, h1, hs, cs, t0);
    }
    // ---- layer 2: Wn/Un/bn on h1, keep only last hidden state (in hs) ----
    for (int ch = 0; ch < NCHUNK; ++ch) {
        const int t0 = ch * TC;
        gemm_proj<<<ggrid, 256, 0, stream>>>(h1, Wn, bn, xzbuf, t0);
        lstm_chunk<<<B_DIM, 512, 0, stream>>>(xzbuf, Pn, nullptr, nullptr, hs, cs, t0);
    }
    // ---- final projection ----
    final_proj<<<B_DIM, 256, 0, stream>>>(h1, hs, Wd, bd, y);
}